// Round 11
// baseline (1975.563 us; speedup 1.0000x reference)
//
#include <hip/hip_runtime.h>
#include <hip/hip_bf16.h>

#define NN 512
#define DEG 8
#define FD 128
#define HD 256
#define MD 256
#define OD 64
#define PD 2
#define HIST 10
#define TOTAL (10 * NN)       /* 5120 queue entries processed */
#define NPAR 648              /* entries with children: i < (TOTAL-S)/8 <= 632 */
#define MAXL 32               /* parallel levels; level MAXL-1 = sequential tail */
#define MAXSW 64              /* Jacobi sweep cap (early-exit typical ~10) */
#define BATCH 8               /* entries per block in k_level */
#define INV_SQRT_H 0.0625f

typedef __hip_bfloat16 bf16;

__device__ __forceinline__ float finz(float x) {
  unsigned u = __float_as_uint(x);
  return (((u >> 23) & 0xFFu) == 0xFFu) ? 0.f : x;
}

__device__ __forceinline__ float ldin(const void* p, int idx, int bf) {
  if (bf) return __bfloat162float(((const bf16*)p)[idx]);
  return ((const float*)p)[idx];
}

// ---- static device scratch ----
__device__ __attribute__((aligned(16))) float g_hist[NN * HIST * HD];  // 5.24 MB
__device__ __attribute__((aligned(16))) float g_msgb[NPAR * MD];
__device__ __attribute__((aligned(16))) float g_WQK[HD * HD];   // Wq @ Wk^T
__device__ __attribute__((aligned(16))) float g_WrS[HD * HD];   // sum of 4 Wr blocks
__device__ __attribute__((aligned(16))) float g_WkT[HD * HD];   // Wk transposed (f32)
__device__ __attribute__((aligned(16))) float g_vq[HD];         // Wq @ bk
__device__ __attribute__((aligned(16))) float g_ck[HD];         // Wk @ bq
__device__ float g_bqk;                     // bq . bk
__device__ int   g_node[TOTAL];
__device__ int   g_rank[TOTAL];
__device__ int   g_np[TOTAL];
__device__ int   g_counts[NN];
__device__ int   g_list[TOTAL];
__device__ int   g_meta[2 * MAXL];
__device__ int   g_dtype;
__device__ int   g_i64;

__device__ __forceinline__ int decode_S(const int* dS) {
  int r = dS[0];
  if (r >= 1 && r <= NN) return r;
  float f = __int_as_float(r);
  if (f >= 1.f && f <= (float)NN) return (int)f;
  unsigned u = ((unsigned)r & 0xFFFFu) << 16;
  float g = __uint_as_float(u);
  if (g >= 1.f && g <= (float)NN) return (int)g;
  return 64;
}

__device__ __forceinline__ int get_nbr(const int* nbrs, int i64, int n, int d) {
  int v = i64 ? nbrs[2 * (n * DEG + d)] : nbrs[n * DEG + d];
  return (v < 0) ? 0 : (v >= NN ? NN - 1 : v);
}

// batched 8-entry matvec: acc[b] += sum_r s_src[b][r] * W[r*HD+t]  (W fp32)
__device__ __forceinline__ void mv8_f32(const float (*s_src)[HD], const float* __restrict__ W,
                                        int t, float acc[BATCH]) {
#pragma unroll 2
  for (int r = 0; r < HD; r += 4) {
    float4 m[BATCH];
#pragma unroll
    for (int b = 0; b < BATCH; ++b) m[b] = *(const float4*)&s_src[b][r];
    const float w0 = W[(r + 0) * HD + t], w1 = W[(r + 1) * HD + t];
    const float w2 = W[(r + 2) * HD + t], w3 = W[(r + 3) * HD + t];
#pragma unroll
    for (int b = 0; b < BATCH; ++b)
      acc[b] += m[b].x * w0 + m[b].y * w1 + m[b].z * w2 + m[b].w * w3;
  }
}

// same but W in raw input dtype (bf16 or f32), row offset ro into W's row index
__device__ __forceinline__ void mv8_dyn(const float (*s_src)[HD], const void* __restrict__ W,
                                        int bf, int ro, int t, float acc[BATCH]) {
#pragma unroll 2
  for (int r = 0; r < HD; r += 4) {
    float4 m[BATCH];
#pragma unroll
    for (int b = 0; b < BATCH; ++b) m[b] = *(const float4*)&s_src[b][r];
    const float w0 = ldin(W, (ro + r + 0) * MD + t, bf);
    const float w1 = ldin(W, (ro + r + 1) * MD + t, bf);
    const float w2 = ldin(W, (ro + r + 2) * MD + t, bf);
    const float w3 = ldin(W, (ro + r + 3) * MD + t, bf);
#pragma unroll
    for (int b = 0; b < BATCH; ++b)
      acc[b] += m[b].x * w0 + m[b].y * w1 + m[b].z * w2 + m[b].w * w3;
  }
}

// ---------------- phase A: dtype detect + BFS expansion ----------------
__global__ void __launch_bounds__(1024)
k_bfs(const unsigned* __restrict__ xa_w, const int* __restrict__ nbrs,
      const int* __restrict__ dS) {
  __shared__ int s_node[TOTAL];
  __shared__ int s_flags[1];
  const int t = threadIdx.x;
  if (t < 64) {
    unsigned lo = xa_w[t] & 0xFFFFu;
    float av = fabsf(__uint_as_float(lo << 16));
    unsigned long long mb = __ballot(av > 0.000244140625f && av < 64.f);
    bool zok = ((t & 1) && t < 16) ? (nbrs[t] == 0) : true;
    unsigned long long mz = __ballot(zok);
    if (t == 0) {
      g_dtype = (__popcll(mb) >= 32) ? 1 : 0;
      int i64 = (mz == ~0ull) ? 1 : 0;
      g_i64 = i64;
      s_flags[0] = i64;
    }
  }
  __syncthreads();
  const int i64 = s_flags[0];
  const int S = decode_S(dS);
  for (int i = t; i < S; i += 1024) s_node[i] = i;
  __syncthreads();
  int done = S;
  while (done < TOTAL) {
    long long nd = (long long)S + 8LL * (long long)done;
    int new_done = nd > (long long)TOTAL ? TOTAL : (int)nd;
    for (int i = done + t; i < new_done; i += 1024)
      s_node[i] = get_nbr(nbrs, i64, s_node[(i - S) >> 3], (i - S) & 7);
    __syncthreads();
    done = new_done;
  }
  for (int i = t; i < TOTAL; i += 1024) g_node[i] = s_node[i];
}

// ---------------- tiled transpose: g_WkT[h][t] = Wk[t][h] (f32) ----------------
__global__ void __launch_bounds__(256)
k_tr(const void* __restrict__ Wk) {
  __shared__ float tile[64][65];
  const int bf = g_dtype;
  const int bx = blockIdx.x & 3, by = blockIdx.x >> 2;
  const int lane = threadIdx.x & 63, tr = threadIdx.x >> 6;
#pragma unroll
  for (int it = 0; it < 16; ++it) {
    const int rl = tr + 4 * it;
    tile[rl][lane] = ldin(Wk, (by * 64 + rl) * HD + bx * 64 + lane, bf);
  }
  __syncthreads();
#pragma unroll
  for (int it = 0; it < 16; ++it) {
    const int rl = tr + 4 * it;
    g_WkT[(bx * 64 + rl) * HD + by * 64 + lane] = tile[lane][rl];
  }
}

// ---------------- phase B: rank + prev-occurrence, ballot-parallel ----------------
__global__ void __launch_bounds__(64)
k_rank() {
  const int n = blockIdx.x;
  const int l = threadIdx.x;
  int k = 0, last = -1;
  for (int base = 0; base < TOTAL; base += 64) {
    int nd = g_node[base + l];
    unsigned long long m = __ballot(nd == n);
    if (nd == n) {
      unsigned long long below = m & ((1ull << l) - 1ull);
      g_rank[base + l] = k + (int)__popcll(below);
      g_np[base + l] = below ? (base + 63 - (int)__builtin_clzll(below)) : last;
    }
    if (m) last = base + 63 - (int)__builtin_clzll(m);
    k += (int)__popcll(m);
  }
  if (l == 0) g_counts[n] = k;
}

// ---------------- phase C: levels + buckets ----------------
__global__ void __launch_bounds__(1024)
k_lvl(const int* __restrict__ dS) {
  __shared__ int   s_np[TOTAL];
  __shared__ short s_lvl[TOTAL];
  __shared__ int   s_lc[MAXL], s_ls[MAXL], s_cur[MAXL];
  __shared__ int   s_chg;
  const int t = threadIdx.x;
  const int S = decode_S(dS);
  for (int i = t; i < TOTAL; i += 1024) { s_np[i] = g_np[i]; s_lvl[i] = 0; }
  for (int l = t; l < MAXL; l += 1024) s_lc[l] = 0;
  __syncthreads();
  for (int sw = 0; sw < MAXSW; ++sw) {
    if (t == 0) s_chg = 0;
    __syncthreads();
    for (int ch = 0; ch < TOTAL; ch += 1024) {
      const int i = ch + t;
      int a = -1;
      int np = s_np[i];
      if (np >= 0) a = s_lvl[np];
      if (i >= S) { int b = s_lvl[(i - S) >> 3]; if (b > a) a = b; }
      int nl = a + 1;
      if (nl > MAXL - 1) nl = MAXL - 1;
      if (nl > (int)s_lvl[i]) { s_lvl[i] = (short)nl; s_chg = 1; }
      __syncthreads();
    }
    if (!s_chg) break;
    __syncthreads();
  }
  __syncthreads();
  for (int i = t; i < TOTAL; i += 1024) atomicAdd(&s_lc[s_lvl[i]], 1);
  __syncthreads();
  if (t == 0) {
    int acc = 0;
    for (int l = 0; l < MAXL; ++l) { s_ls[l] = acc; s_cur[l] = acc; acc += s_lc[l]; }
  }
  __syncthreads();
  for (int i = t; i < TOTAL; i += 1024) {
    int l = s_lvl[i];
    if (l < MAXL - 1) g_list[atomicAdd(&s_cur[l], 1)] = i;
  }
  if (t < MAXL) { g_meta[2 * t] = s_ls[t]; g_meta[2 * t + 1] = s_lc[t]; }
  __syncthreads();
  if (t < 64) {                              // tail: index-ascending ballot scan
    int pos = s_ls[MAXL - 1];
    for (int base = 0; base < TOTAL; base += 64) {
      bool sel = (s_lvl[base + t] == MAXL - 1);
      unsigned long long m = __ballot(sel);
      if (sel) g_list[pos + (int)__popcll(m & ((1ull << t) - 1ull))] = base + t;
      pos += (int)__popcll(m);
    }
  }
}

// ---------------- WQK fold, batched 8 rows/block (32 blocks) + vq ----------------
__global__ void __launch_bounds__(256)
k_wqk(const void* __restrict__ Wq, const void* __restrict__ bk) {
  __shared__ float s_src[BATCH][HD];
  __shared__ float s_red[BATCH][4];
  const int t = threadIdx.x;
  const int bf = g_dtype;
  const int wave = t >> 6, lane = t & 63;
  const int R = blockIdx.x * BATCH;
#pragma unroll
  for (int b = 0; b < BATCH; ++b) s_src[b][t] = ldin(Wq, (R + b) * HD + t, bf);
  __syncthreads();
  float acc[BATCH];
#pragma unroll
  for (int b = 0; b < BATCH; ++b) acc[b] = 0.f;
  mv8_f32(s_src, g_WkT, t, acc);
#pragma unroll
  for (int b = 0; b < BATCH; ++b) g_WQK[(R + b) * HD + t] = acc[b];
  // vq[R+b] = Wq row (R+b) . bk
  const float bkv = ldin(bk, t, bf);
#pragma unroll
  for (int b = 0; b < BATCH; ++b) {
    float pv = s_src[b][t] * bkv;
#pragma unroll
    for (int off = 32; off > 0; off >>= 1) pv += __shfl_down(pv, off, 64);
    if (lane == 0) s_red[b][wave] = pv;
  }
  __syncthreads();
  if (t < BATCH) g_vq[R + t] = s_red[t][0] + s_red[t][1] + s_red[t][2] + s_red[t][3];
}

// ---------------- WrS fold + ck/bqk + encode ----------------
__global__ void __launch_bounds__(256)
k_weights(const void* __restrict__ xa, const void* __restrict__ We,
          const void* __restrict__ be, const void* __restrict__ Wr,
          const void* __restrict__ bq, const void* __restrict__ bk) {
  const int b = blockIdx.x, t = threadIdx.x;
  const int bf = g_dtype;
  const int wave = t >> 6, lane = t & 63;
  __shared__ float sw[HD];
  __shared__ float sr[4];
  if (b < HD) {
    float s = 0.f;
#pragma unroll
    for (int q = 0; q < 4; ++q) s += ldin(Wr, (q * HD + b) * HD + t, bf);
    g_WrS[b * HD + t] = s;
  } else if (b == HD) {
    sw[t] = ldin(bq, t, bf);
    __syncthreads();
    float a0 = 0.f, a1 = 0.f;                        // ck[t] = sum_h bq[h]*WkT[h][t]
    for (int h = 0; h < HD; h += 2) {
      a0 += sw[h] * g_WkT[h * HD + t];
      a1 += sw[h + 1] * g_WkT[(h + 1) * HD + t];
    }
    g_ck[t] = a0 + a1;
    float pb = sw[t] * ldin(bk, t, bf);
#pragma unroll
    for (int off = 32; off > 0; off >>= 1) pb += __shfl_down(pb, off, 64);
    if (lane == 0) sr[wave] = pb;
    __syncthreads();
    if (t == 0) g_bqk = sr[0] + sr[1] + sr[2] + sr[3];
  } else {
    const int n = b - HD - 1;
    if (t < FD) sw[t] = ldin(xa, n * FD + t, bf);
    __syncthreads();
    float acc = ldin(be, t, bf);
    for (int f = 0; f < FD; ++f) acc += sw[f] * ldin(We, f * HD + t, bf);
    g_hist[(size_t)(n * HIST) * HD + t] = acc;
  }
}

// ---------------- batched group of up to 8 level-independent entries ----------------
__device__ __forceinline__ void group8(
    int base, int m, int S, int t, int bf, int vol,
    float (*s_msg)[HD], float (*s_kq)[HD], float (*s_vals)[HD], float (*s_ns)[HD],
    int* s_de, int* s_dn, int* s_dk, int* s_dp, int* s_dh, int* s_dv,
    const void* fmsg, const void* br_, const void* Wm, const void* bm) {
  const int wave = t >> 6, lane = t & 63;

  if (t < BATCH) {
    int valid = (t < m) ? 1 : 0;
    int e = valid ? g_list[base + t] : 0;
    int n = 0, k = 0, p = 0, hc = 0;
    if (valid) {
      n = g_node[e]; k = g_rank[e];
      p = (e >= S) ? ((e - S) >> 3) : 0;
      hc = ((S + 8 * e) < TOTAL) ? 1 : 0;
    }
    s_de[t] = e; s_dn[t] = n; s_dk[t] = k; s_dp[t] = p; s_dh[t] = hc; s_dv[t] = valid;
  }
  __syncthreads();

  // messages (col t for each entry)
#pragma unroll
  for (int b = 0; b < BATCH; ++b) {
    float v = 0.f;
    if (s_dv[b]) {
      int e = s_de[b];
      if (e < S) v = ldin(fmsg, e * MD + t, bf);
      else if (vol) v = finz(((volatile const float*)g_msgb)[(size_t)s_dp[b] * MD + t]);
      else v = finz(g_msgb[(size_t)s_dp[b] * MD + t]);
    }
    s_msg[b][t] = v;
  }
  __syncthreads();

  // kq = msg @ WQK + ck (batched)
  {
    float acc[BATCH];
    const float ckt = g_ck[t];
#pragma unroll
    for (int b = 0; b < BATCH; ++b) acc[b] = ckt;
    mv8_f32(s_msg, g_WQK, t, acc);
#pragma unroll
    for (int b = 0; b < BATCH; ++b) s_kq[b][t] = acc[b];
  }
  __syncthreads();

  // attention: wave w handles entries w and w+4 (wave-local, no barriers)
  for (int eb = wave; eb < BATCH; eb += 4) {
    if (!s_dv[eb]) {
      *(float4*)&s_vals[eb][4 * lane] = make_float4(0.f, 0.f, 0.f, 0.f);
      continue;
    }
    const int n = s_dn[eb], k = s_dk[eb];
    const int c = k + 1;
    const int v = (c < HIST) ? c : HIST;
    float4 fj[HIST];
#pragma unroll
    for (int j = 0; j < HIST; ++j) {
      if (j < v) {
        const size_t off = (size_t)(n * HIST + j) * HD + 4 * lane;
        if (vol) {
          volatile const float* vh = g_hist;
          fj[j] = make_float4(finz(vh[off]), finz(vh[off + 1]),
                              finz(vh[off + 2]), finz(vh[off + 3]));
        } else {
          float4 x = *(const float4*)&g_hist[off];
          fj[j] = make_float4(finz(x.x), finz(x.y), finz(x.z), finz(x.w));
        }
      } else fj[j] = make_float4(0.f, 0.f, 0.f, 0.f);
    }
    const float4 kq4 = *(const float4*)&s_kq[eb][4 * lane];
    const float4 mq4 = *(const float4*)&s_msg[eb][4 * lane];
    const float4 vq4 = *(const float4*)&g_vq[4 * lane];
    float part[HIST + 1];
#pragma unroll
    for (int j = 0; j < HIST; ++j)
      part[j] = fj[j].x * kq4.x + fj[j].y * kq4.y + fj[j].z * kq4.z + fj[j].w * kq4.w;
    part[HIST] = mq4.x * vq4.x + mq4.y * vq4.y + mq4.z * vq4.z + mq4.w * vq4.w;
#pragma unroll
    for (int off = 32; off > 0; off >>= 1) {
#pragma unroll
      for (int j = 0; j <= HIST; ++j) part[j] += __shfl_xor(part[j], off, 64);
    }
    const float bkq = part[HIST] + g_bqk;
    float lg[HIST];
#pragma unroll
    for (int j = 0; j < HIST; ++j)
      lg[j] = (j < v) ? ((part[j] + bkq) * INV_SQRT_H) : -1e30f;
    float mx = lg[0];
#pragma unroll
    for (int j = 1; j < HIST; ++j) mx = fmaxf(mx, lg[j]);
    float e_[HIST], den = 0.f;
#pragma unroll
    for (int j = 0; j < HIST; ++j) { e_[j] = __expf(lg[j] - mx); den += e_[j]; }
    const float iden = 1.0f / den;
    float4 val = make_float4(0.f, 0.f, 0.f, 0.f);
#pragma unroll
    for (int j = 0; j < HIST; ++j) {
      val.x += e_[j] * fj[j].x; val.y += e_[j] * fj[j].y;
      val.z += e_[j] * fj[j].z; val.w += e_[j] * fj[j].w;
    }
    val.x *= iden; val.y *= iden; val.z *= iden; val.w *= iden;
    *(float4*)&s_vals[eb][4 * lane] = val;
  }
  __syncthreads();

  // newstate = vals @ WrS + br (batched) -> hist + s_ns
  {
    float acc[BATCH];
    const float brt = ldin(br_, t, bf);
#pragma unroll
    for (int b = 0; b < BATCH; ++b) acc[b] = brt;
    mv8_f32(s_vals, g_WrS, t, acc);
#pragma unroll
    for (int b = 0; b < BATCH; ++b) {
      if (s_dv[b]) {
        const int slot = (s_dk[b] + 1) % HIST;
        g_hist[(size_t)(s_dn[b] * HIST + slot) * HD + t] = acc[b];
        s_ns[b][t] = acc[b];
      } else s_ns[b][t] = 0.f;
    }
  }
  __syncthreads();

  // newmessage = [ns, msg] @ Wm + bm (batched, raw dtype)
  {
    float acc[BATCH];
    const float bmt = ldin(bm, t, bf);
#pragma unroll
    for (int b = 0; b < BATCH; ++b) acc[b] = bmt;
    mv8_dyn(s_ns, Wm, bf, 0, t, acc);
    mv8_dyn(s_msg, Wm, bf, HD, t, acc);
#pragma unroll
    for (int b = 0; b < BATCH; ++b)
      if (s_dv[b] && s_dh[b]) g_msgb[(size_t)s_de[b] * MD + t] = acc[b];
  }
  __syncthreads();   // LDS reuse guard
}

// ---------------- per-level executor: 8 entries per block ----------------
__global__ void __launch_bounds__(256)
k_level(const void* __restrict__ fmsg, const void* __restrict__ br_,
        const void* __restrict__ Wm, const void* __restrict__ bm,
        const int* __restrict__ dS, int lvl, int seq) {
  const int t = threadIdx.x;
  const int S = decode_S(dS);
  const int bf = g_dtype;
  const int start = g_meta[2 * lvl], count = g_meta[2 * lvl + 1];
  __shared__ float s_msg[BATCH][HD];
  __shared__ float s_kq[BATCH][HD];
  __shared__ float s_vals[BATCH][HD];
  __shared__ float s_ns[BATCH][HD];
  __shared__ int s_de[BATCH], s_dn[BATCH], s_dk[BATCH], s_dp[BATCH],
                 s_dh[BATCH], s_dv[BATCH];
  if (seq) {
    if (blockIdx.x != 0) return;       // strict index order; volatile reads
    for (int idx = 0; idx < count; ++idx)
      group8(start + idx, 1, S, t, bf, 1, s_msg, s_kq, s_vals, s_ns,
             s_de, s_dn, s_dk, s_dp, s_dh, s_dv, fmsg, br_, Wm, bm);
  } else {
    const int ngroups = (count + BATCH - 1) / BATCH;
    for (int g = (int)blockIdx.x; g < ngroups; g += (int)gridDim.x) {
      const int base = start + g * BATCH;
      const int m = (count - g * BATCH < BATCH) ? (count - g * BATCH) : BATCH;
      group8(base, m, S, t, bf, 0, s_msg, s_kq, s_vals, s_ns,
             s_de, s_dn, s_dk, s_dp, s_dh, s_dv, fmsg, br_, Wm, bm);
    }
  }
}

// ---------------- final projection + log_softmax ----------------
__global__ void k_out(const void* __restrict__ Wd, const void* __restrict__ bd,
                      void* __restrict__ out) {
  __shared__ float sf[HD];
  const int b = blockIdx.x;
  const int pp = b >> 9;
  const int n = b & 511;
  const int t = threadIdx.x;
  const int bf = g_dtype;
  int occ = g_counts[n];
  if (occ < 0 || occ > TOTAL) occ = 0;
  const int slot = occ % HIST;
  for (int h = t; h < HD; h += OD) sf[h] = finz(g_hist[(size_t)(n * HIST + slot) * HD + h]);
  __syncthreads();
  float acc = finz(ldin(bd, pp * OD + t, bf));
  for (int h = 0; h < HD; ++h) acc += sf[h] * ldin(Wd, (pp * HD + h) * OD + t, bf);
  acc = finz(acc);
  float mx = acc;
#pragma unroll
  for (int off = 32; off > 0; off >>= 1) mx = fmaxf(mx, __shfl_xor(mx, off, 64));
  float ex = __expf(acc - mx);
  float s = ex;
#pragma unroll
  for (int off = 32; off > 0; off >>= 1) s += __shfl_xor(s, off, 64);
  float r = finz(acc - mx - logf(s));
  const int oi = (pp * NN + n) * OD + t;
  if (bf) ((bf16*)out)[oi] = __float2bfloat16(r);
  else    ((float*)out)[oi] = r;
}

extern "C" void kernel_launch(void* const* d_in, const int* in_sizes, int n_in,
                              void* d_out, int out_size, void* d_ws, size_t ws_size,
                              hipStream_t stream) {
  const void* xa   = d_in[0];
  const int*  nbrs = (const int*)d_in[1];
  const void* fmsg = d_in[2];
  const void* We   = d_in[3];
  const void* be   = d_in[4];
  const void* Wq   = d_in[5];
  const void* bq   = d_in[6];
  const void* Wk   = d_in[7];
  const void* bk   = d_in[8];
  const void* Wr   = d_in[9];
  const void* br   = d_in[10];
  const void* Wm   = d_in[11];
  const void* bm   = d_in[12];
  const void* Wd   = d_in[13];
  const void* bd   = d_in[14];
  const int*  dS   = (const int*)d_in[15];
  (void)d_ws; (void)ws_size; (void)in_sizes; (void)n_in; (void)out_size;

  k_bfs<<<dim3(1), dim3(1024), 0, stream>>>((const unsigned*)xa, nbrs, dS);
  k_tr<<<dim3(16), dim3(256), 0, stream>>>(Wk);
  k_rank<<<dim3(NN), dim3(64), 0, stream>>>();
  k_lvl<<<dim3(1), dim3(1024), 0, stream>>>(dS);
  k_weights<<<dim3(HD + 1 + NN), dim3(256), 0, stream>>>(xa, We, be, Wr, bq, bk);
  k_wqk<<<dim3(HD / BATCH), dim3(256), 0, stream>>>(Wq, bk);
  for (int l = 0; l < MAXL - 1; ++l)
    k_level<<<dim3(128), dim3(256), 0, stream>>>(fmsg, br, Wm, bm, dS, l, 0);
  k_level<<<dim3(1), dim3(256), 0, stream>>>(fmsg, br, Wm, bm, dS, MAXL - 1, 1);
  k_out<<<dim3(PD * NN), dim3(OD), 0, stream>>>(Wd, bd, d_out);
}

// Round 12
// 747.326 us; speedup vs baseline: 2.6435x; 2.6435x over previous
//
#include <hip/hip_runtime.h>
#include <hip/hip_bf16.h>

#define NN 512
#define DEG 8
#define FD 128
#define HD 256
#define MD 256
#define OD 64
#define PD 2
#define HIST 10
#define TOTAL (10 * NN)       /* 5120 queue entries processed */
#define NPAR 648              /* entries with children: i < (TOTAL-S)/8 <= 632 */
#define MAXL 32               /* parallel levels; level MAXL-1 = sequential tail */
#define MAXSW 64              /* Jacobi sweep cap (early-exit typical ~10) */
#define BATCH 8               /* rows per block in k_wqk */
#define INV_SQRT_H 0.0625f

typedef __hip_bfloat16 bf16;

__device__ __forceinline__ float finz(float x) {
  unsigned u = __float_as_uint(x);
  return (((u >> 23) & 0xFFu) == 0xFFu) ? 0.f : x;
}

__device__ __forceinline__ float ldin(const void* p, int idx, int bf) {
  if (bf) return __bfloat162float(((const bf16*)p)[idx]);
  return ((const float*)p)[idx];
}

// ---- static device scratch ----
__device__ __attribute__((aligned(16))) float g_hist[NN * HIST * HD];  // 5.24 MB
__device__ __attribute__((aligned(16))) float g_msgb[NPAR * MD];
__device__ __attribute__((aligned(16))) float g_WQK[HD * HD];   // Wq @ Wk^T
__device__ __attribute__((aligned(16))) float g_WrS[HD * HD];   // sum of 4 Wr blocks
__device__ __attribute__((aligned(16))) float g_WkT[HD * HD];   // Wk transposed (f32)
__device__ __attribute__((aligned(16))) float g_vq[HD];         // Wq @ bk
__device__ __attribute__((aligned(16))) float g_ck[HD];         // Wk @ bq
__device__ float g_bqk;                     // bq . bk
__device__ int   g_node[TOTAL];
__device__ int   g_rank[TOTAL];
__device__ int   g_np[TOTAL];
__device__ int   g_counts[NN];
__device__ int   g_list[TOTAL];
__device__ int   g_meta[2 * MAXL];
__device__ int   g_dtype;
__device__ int   g_i64;

__device__ __forceinline__ int decode_S(const int* dS) {
  int r = dS[0];
  if (r >= 1 && r <= NN) return r;
  float f = __int_as_float(r);
  if (f >= 1.f && f <= (float)NN) return (int)f;
  unsigned u = ((unsigned)r & 0xFFFFu) << 16;
  float g = __uint_as_float(u);
  if (g >= 1.f && g <= (float)NN) return (int)g;
  return 64;
}

__device__ __forceinline__ int get_nbr(const int* nbrs, int i64, int n, int d) {
  int v = i64 ? nbrs[2 * (n * DEG + d)] : nbrs[n * DEG + d];
  return (v < 0) ? 0 : (v >= NN ? NN - 1 : v);
}

// ---------------- phase A: dtype detect + BFS expansion ----------------
__global__ void __launch_bounds__(1024)
k_bfs(const unsigned* __restrict__ xa_w, const int* __restrict__ nbrs,
      const int* __restrict__ dS) {
  __shared__ int s_node[TOTAL];
  __shared__ int s_flags[1];
  const int t = threadIdx.x;
  if (t < 64) {
    unsigned lo = xa_w[t] & 0xFFFFu;
    float av = fabsf(__uint_as_float(lo << 16));
    unsigned long long mb = __ballot(av > 0.000244140625f && av < 64.f);
    bool zok = ((t & 1) && t < 16) ? (nbrs[t] == 0) : true;
    unsigned long long mz = __ballot(zok);
    if (t == 0) {
      g_dtype = (__popcll(mb) >= 32) ? 1 : 0;
      int i64 = (mz == ~0ull) ? 1 : 0;
      g_i64 = i64;
      s_flags[0] = i64;
    }
  }
  __syncthreads();
  const int i64 = s_flags[0];
  const int S = decode_S(dS);
  for (int i = t; i < S; i += 1024) s_node[i] = i;
  __syncthreads();
  int done = S;
  while (done < TOTAL) {
    long long nd = (long long)S + 8LL * (long long)done;
    int new_done = nd > (long long)TOTAL ? TOTAL : (int)nd;
    for (int i = done + t; i < new_done; i += 1024)
      s_node[i] = get_nbr(nbrs, i64, s_node[(i - S) >> 3], (i - S) & 7);
    __syncthreads();
    done = new_done;
  }
  for (int i = t; i < TOTAL; i += 1024) g_node[i] = s_node[i];
}

// ---------------- tiled transpose: g_WkT[h][t] = Wk[t][h] (f32) ----------------
__global__ void __launch_bounds__(256)
k_tr(const void* __restrict__ Wk) {
  __shared__ float tile[64][65];
  const int bf = g_dtype;
  const int bx = blockIdx.x & 3, by = blockIdx.x >> 2;
  const int lane = threadIdx.x & 63, tr = threadIdx.x >> 6;
#pragma unroll
  for (int it = 0; it < 16; ++it) {
    const int rl = tr + 4 * it;
    tile[rl][lane] = ldin(Wk, (by * 64 + rl) * HD + bx * 64 + lane, bf);
  }
  __syncthreads();
#pragma unroll
  for (int it = 0; it < 16; ++it) {
    const int rl = tr + 4 * it;
    g_WkT[(bx * 64 + rl) * HD + by * 64 + lane] = tile[lane][rl];
  }
}

// ---------------- phase B: rank + prev-occurrence, ballot-parallel ----------------
__global__ void __launch_bounds__(64)
k_rank() {
  const int n = blockIdx.x;
  const int l = threadIdx.x;
  int k = 0, last = -1;
  for (int base = 0; base < TOTAL; base += 64) {
    int nd = g_node[base + l];
    unsigned long long m = __ballot(nd == n);
    if (nd == n) {
      unsigned long long below = m & ((1ull << l) - 1ull);
      g_rank[base + l] = k + (int)__popcll(below);
      g_np[base + l] = below ? (base + 63 - (int)__builtin_clzll(below)) : last;
    }
    if (m) last = base + 63 - (int)__builtin_clzll(m);
    k += (int)__popcll(m);
  }
  if (l == 0) g_counts[n] = k;
}

// ---------------- phase C: levels + buckets ----------------
__global__ void __launch_bounds__(1024)
k_lvl(const int* __restrict__ dS) {
  __shared__ int   s_np[TOTAL];
  __shared__ short s_lvl[TOTAL];
  __shared__ int   s_lc[MAXL], s_ls[MAXL], s_cur[MAXL];
  __shared__ int   s_chg;
  const int t = threadIdx.x;
  const int S = decode_S(dS);
  for (int i = t; i < TOTAL; i += 1024) { s_np[i] = g_np[i]; s_lvl[i] = 0; }
  for (int l = t; l < MAXL; l += 1024) s_lc[l] = 0;
  __syncthreads();
  for (int sw = 0; sw < MAXSW; ++sw) {
    if (t == 0) s_chg = 0;
    __syncthreads();
    for (int ch = 0; ch < TOTAL; ch += 1024) {
      const int i = ch + t;
      int a = -1;
      int np = s_np[i];
      if (np >= 0) a = s_lvl[np];
      if (i >= S) { int b = s_lvl[(i - S) >> 3]; if (b > a) a = b; }
      int nl = a + 1;
      if (nl > MAXL - 1) nl = MAXL - 1;
      if (nl > (int)s_lvl[i]) { s_lvl[i] = (short)nl; s_chg = 1; }
      __syncthreads();
    }
    if (!s_chg) break;
    __syncthreads();
  }
  __syncthreads();
  for (int i = t; i < TOTAL; i += 1024) atomicAdd(&s_lc[s_lvl[i]], 1);
  __syncthreads();
  if (t == 0) {
    int acc = 0;
    for (int l = 0; l < MAXL; ++l) { s_ls[l] = acc; s_cur[l] = acc; acc += s_lc[l]; }
  }
  __syncthreads();
  for (int i = t; i < TOTAL; i += 1024) {
    int l = s_lvl[i];
    if (l < MAXL - 1) g_list[atomicAdd(&s_cur[l], 1)] = i;
  }
  if (t < MAXL) { g_meta[2 * t] = s_ls[t]; g_meta[2 * t + 1] = s_lc[t]; }
  __syncthreads();
  if (t < 64) {                              // tail: index-ascending ballot scan
    int pos = s_ls[MAXL - 1];
    for (int base = 0; base < TOTAL; base += 64) {
      bool sel = (s_lvl[base + t] == MAXL - 1);
      unsigned long long m = __ballot(sel);
      if (sel) g_list[pos + (int)__popcll(m & ((1ull << t) - 1ull))] = base + t;
      pos += (int)__popcll(m);
    }
  }
}

// ---------------- WQK fold, batched 8 rows/block (32 blocks) + vq ----------------
__global__ void __launch_bounds__(256)
k_wqk(const void* __restrict__ Wq, const void* __restrict__ bk) {
  __shared__ float s_src[BATCH][HD];
  __shared__ float s_red[BATCH][4];
  const int t = threadIdx.x;
  const int bf = g_dtype;
  const int wave = t >> 6, lane = t & 63;
  const int R = blockIdx.x * BATCH;
#pragma unroll
  for (int b = 0; b < BATCH; ++b) s_src[b][t] = ldin(Wq, (R + b) * HD + t, bf);
  __syncthreads();
  float acc[BATCH];
#pragma unroll
  for (int b = 0; b < BATCH; ++b) acc[b] = 0.f;
#pragma unroll 2
  for (int r = 0; r < HD; r += 4) {
    const float w0 = g_WkT[(r + 0) * HD + t], w1 = g_WkT[(r + 1) * HD + t];
    const float w2 = g_WkT[(r + 2) * HD + t], w3 = g_WkT[(r + 3) * HD + t];
#pragma unroll
    for (int b = 0; b < BATCH; ++b)
      acc[b] += s_src[b][r] * w0 + s_src[b][r + 1] * w1 +
                s_src[b][r + 2] * w2 + s_src[b][r + 3] * w3;
  }
#pragma unroll
  for (int b = 0; b < BATCH; ++b) g_WQK[(R + b) * HD + t] = acc[b];
  const float bkv = ldin(bk, t, bf);
#pragma unroll
  for (int b = 0; b < BATCH; ++b) {
    float pv = s_src[b][t] * bkv;
#pragma unroll
    for (int off = 32; off > 0; off >>= 1) pv += __shfl_down(pv, off, 64);
    if (lane == 0) s_red[b][wave] = pv;
  }
  __syncthreads();
  if (t < BATCH) g_vq[R + t] = s_red[t][0] + s_red[t][1] + s_red[t][2] + s_red[t][3];
}

// ---------------- WrS fold + ck/bqk + encode ----------------
__global__ void __launch_bounds__(256)
k_weights(const void* __restrict__ xa, const void* __restrict__ We,
          const void* __restrict__ be, const void* __restrict__ Wr,
          const void* __restrict__ bq, const void* __restrict__ bk) {
  const int b = blockIdx.x, t = threadIdx.x;
  const int bf = g_dtype;
  const int wave = t >> 6, lane = t & 63;
  __shared__ float sw[HD];
  __shared__ float sr[4];
  if (b < HD) {
    float s = 0.f;
#pragma unroll
    for (int q = 0; q < 4; ++q) s += ldin(Wr, (q * HD + b) * HD + t, bf);
    g_WrS[b * HD + t] = s;
  } else if (b == HD) {
    sw[t] = ldin(bq, t, bf);
    __syncthreads();
    float a0 = 0.f, a1 = 0.f;                        // ck[t] = sum_h bq[h]*WkT[h][t]
    for (int h = 0; h < HD; h += 2) {
      a0 += sw[h] * g_WkT[h * HD + t];
      a1 += sw[h + 1] * g_WkT[(h + 1) * HD + t];
    }
    g_ck[t] = a0 + a1;
    float pb = sw[t] * ldin(bk, t, bf);
#pragma unroll
    for (int off = 32; off > 0; off >>= 1) pb += __shfl_down(pb, off, 64);
    if (lane == 0) sr[wave] = pb;
    __syncthreads();
    if (t == 0) g_bqk = sr[0] + sr[1] + sr[2] + sr[3];
  } else {
    const int n = b - HD - 1;
    if (t < FD) sw[t] = ldin(xa, n * FD + t, bf);
    __syncthreads();
    float acc = ldin(be, t, bf);
    for (int f = 0; f < FD; ++f) acc += sw[f] * ldin(We, f * HD + t, bf);
    g_hist[(size_t)(n * HIST) * HD + t] = acc;
  }
}

// ---------------- one attention step (r9 structure, 8-acc unroll, 256 threads) ----------------
__device__ __forceinline__ void step_body(
    int e, int S, int t, int bf, int vol,
    float* s_msg, float (*s_feats)[HD], float* s_vals, float* s_ns,
    float (*s_red)[HIST + 1], float* s_sc,
    const void* fmsg, const void* br_, const void* Wm, const void* bm) {
  const int n = g_node[e];
  const int k = g_rank[e];
  const int p = (e >= S) ? ((e - S) >> 3) : 0;
  const bool hc = (S + 8 * e) < TOTAL;
  const int c = k + 1;
  const int v = (c < HIST) ? c : HIST;
  const int slot = c % HIST;
  const int wave = t >> 6, lane = t & 63;

  if (e < S) s_msg[t] = ldin(fmsg, e * MD + t, bf);
  else if (vol) s_msg[t] = finz(((volatile const float*)g_msgb)[(size_t)p * MD + t]);
  else s_msg[t] = finz(g_msgb[(size_t)p * MD + t]);
#pragma unroll
  for (int j = 0; j < HIST; ++j) {
    float x = 0.f;
    if (j < v) {
      if (vol) x = ((volatile const float*)g_hist)[(size_t)(n * HIST + j) * HD + t];
      else     x = g_hist[(size_t)(n * HIST + j) * HD + t];
    }
    s_feats[j][t] = finz(x);
  }
  __syncthreads();

  // kq[t] = msg . WQK[:,t] + ck[t]   (8 accumulators, 16 loads in flight)
  float a0 = 0.f, a1 = 0.f, a2 = 0.f, a3 = 0.f, a4 = 0.f, a5 = 0.f, a6 = 0.f, a7 = 0.f;
#pragma unroll 2
  for (int m = 0; m < MD; m += 8) {
    a0 += s_msg[m]     * g_WQK[(m)     * HD + t];
    a1 += s_msg[m + 1] * g_WQK[(m + 1) * HD + t];
    a2 += s_msg[m + 2] * g_WQK[(m + 2) * HD + t];
    a3 += s_msg[m + 3] * g_WQK[(m + 3) * HD + t];
    a4 += s_msg[m + 4] * g_WQK[(m + 4) * HD + t];
    a5 += s_msg[m + 5] * g_WQK[(m + 5) * HD + t];
    a6 += s_msg[m + 6] * g_WQK[(m + 6) * HD + t];
    a7 += s_msg[m + 7] * g_WQK[(m + 7) * HD + t];
  }
  const float kq = g_ck[t] + (((a0 + a1) + (a2 + a3)) + ((a4 + a5) + (a6 + a7)));

  float part[HIST + 1];
#pragma unroll
  for (int j = 0; j < HIST; ++j) part[j] = s_feats[j][t] * kq;
  part[HIST] = s_msg[t] * g_vq[t];
#pragma unroll
  for (int off = 32; off > 0; off >>= 1) {
#pragma unroll
    for (int j = 0; j <= HIST; ++j) part[j] += __shfl_down(part[j], off, 64);
  }
  if (lane == 0) {
#pragma unroll
    for (int j = 0; j <= HIST; ++j) s_red[wave][j] = part[j];
  }
  __syncthreads();
  if (t <= HIST) s_sc[t] = s_red[0][t] + s_red[1][t] + s_red[2][t] + s_red[3][t];
  __syncthreads();

  const float bkq = s_sc[HIST] + g_bqk;
  float lg[HIST];
#pragma unroll
  for (int j = 0; j < HIST; ++j)
    lg[j] = (j < v) ? ((s_sc[j] + bkq) * INV_SQRT_H) : -1e30f;
  float mx = lg[0];
#pragma unroll
  for (int j = 1; j < HIST; ++j) mx = fmaxf(mx, lg[j]);
  float e_[HIST], den = 0.f;
#pragma unroll
  for (int j = 0; j < HIST; ++j) { e_[j] = __expf(lg[j] - mx); den += e_[j]; }
  const float iden = 1.0f / den;
  float val = 0.f;
#pragma unroll
  for (int j = 0; j < HIST; ++j) val += e_[j] * s_feats[j][t];
  s_vals[t] = val * iden;
  __syncthreads();

  // newstate = vals @ WrS + br
  float b0 = 0.f, b1 = 0.f, b2 = 0.f, b3 = 0.f, b4 = 0.f, b5 = 0.f, b6 = 0.f, b7 = 0.f;
#pragma unroll 2
  for (int h = 0; h < HD; h += 8) {
    b0 += s_vals[h]     * g_WrS[(h)     * HD + t];
    b1 += s_vals[h + 1] * g_WrS[(h + 1) * HD + t];
    b2 += s_vals[h + 2] * g_WrS[(h + 2) * HD + t];
    b3 += s_vals[h + 3] * g_WrS[(h + 3) * HD + t];
    b4 += s_vals[h + 4] * g_WrS[(h + 4) * HD + t];
    b5 += s_vals[h + 5] * g_WrS[(h + 5) * HD + t];
    b6 += s_vals[h + 6] * g_WrS[(h + 6) * HD + t];
    b7 += s_vals[h + 7] * g_WrS[(h + 7) * HD + t];
  }
  const float ns = ldin(br_, t, bf) + (((b0 + b1) + (b2 + b3)) + ((b4 + b5) + (b6 + b7)));
  g_hist[(size_t)(n * HIST + slot) * HD + t] = ns;
  if (hc) s_ns[t] = ns;
  __syncthreads();

  // newmessage = [ns, msg] @ Wm + bm  (only entries with children)
  if (hc) {
    float c0 = 0.f, c1 = 0.f, c2 = 0.f, c3 = 0.f, c4 = 0.f, c5 = 0.f, c6 = 0.f, c7 = 0.f;
#pragma unroll 2
    for (int h = 0; h < HD; h += 8) {
      c0 += s_ns[h]     * ldin(Wm, (h)     * MD + t, bf);
      c1 += s_ns[h + 1] * ldin(Wm, (h + 1) * MD + t, bf);
      c2 += s_ns[h + 2] * ldin(Wm, (h + 2) * MD + t, bf);
      c3 += s_ns[h + 3] * ldin(Wm, (h + 3) * MD + t, bf);
      c4 += s_ns[h + 4] * ldin(Wm, (h + 4) * MD + t, bf);
      c5 += s_ns[h + 5] * ldin(Wm, (h + 5) * MD + t, bf);
      c6 += s_ns[h + 6] * ldin(Wm, (h + 6) * MD + t, bf);
      c7 += s_ns[h + 7] * ldin(Wm, (h + 7) * MD + t, bf);
    }
#pragma unroll 2
    for (int m = 0; m < MD; m += 8) {
      c0 += s_msg[m]     * ldin(Wm, (HD + m)     * MD + t, bf);
      c1 += s_msg[m + 1] * ldin(Wm, (HD + m + 1) * MD + t, bf);
      c2 += s_msg[m + 2] * ldin(Wm, (HD + m + 2) * MD + t, bf);
      c3 += s_msg[m + 3] * ldin(Wm, (HD + m + 3) * MD + t, bf);
      c4 += s_msg[m + 4] * ldin(Wm, (HD + m + 4) * MD + t, bf);
      c5 += s_msg[m + 5] * ldin(Wm, (HD + m + 5) * MD + t, bf);
      c6 += s_msg[m + 6] * ldin(Wm, (HD + m + 6) * MD + t, bf);
      c7 += s_msg[m + 7] * ldin(Wm, (HD + m + 7) * MD + t, bf);
    }
    g_msgb[(size_t)e * MD + t] =
        ldin(bm, t, bf) + (((c0 + c1) + (c2 + c3)) + ((c4 + c5) + (c6 + c7)));
  }
  __syncthreads();   // LDS reuse guard
}

// ---------------- per-level executor: 1 entry per block (r9 structure) ----------------
__global__ void __launch_bounds__(256)
k_level(const void* __restrict__ fmsg, const void* __restrict__ br_,
        const void* __restrict__ Wm, const void* __restrict__ bm,
        const int* __restrict__ dS, int lvl, int seq) {
  const int t = threadIdx.x;
  const int S = decode_S(dS);
  const int bf = g_dtype;
  const int start = g_meta[2 * lvl], count = g_meta[2 * lvl + 1];
  __shared__ float s_msg[MD];
  __shared__ float s_feats[HIST][HD];
  __shared__ float s_vals[HD];
  __shared__ float s_ns[HD];
  __shared__ float s_red[4][HIST + 1];
  __shared__ float s_sc[HIST + 1];
  if (seq) {
    if (blockIdx.x != 0) return;       // index-ascending => dependency-safe
    for (int idx = 0; idx < count; ++idx)
      step_body(g_list[start + idx], S, t, bf, 1, s_msg, s_feats, s_vals, s_ns,
                s_red, s_sc, fmsg, br_, Wm, bm);
  } else {
    for (int idx = (int)blockIdx.x; idx < count; idx += (int)gridDim.x)
      step_body(g_list[start + idx], S, t, bf, 0, s_msg, s_feats, s_vals, s_ns,
                s_red, s_sc, fmsg, br_, Wm, bm);
  }
}

// ---------------- final projection + log_softmax ----------------
__global__ void k_out(const void* __restrict__ Wd, const void* __restrict__ bd,
                      void* __restrict__ out) {
  __shared__ float sf[HD];
  const int b = blockIdx.x;
  const int pp = b >> 9;
  const int n = b & 511;
  const int t = threadIdx.x;
  const int bf = g_dtype;
  int occ = g_counts[n];
  if (occ < 0 || occ > TOTAL) occ = 0;
  const int slot = occ % HIST;
  for (int h = t; h < HD; h += OD) sf[h] = finz(g_hist[(size_t)(n * HIST + slot) * HD + h]);
  __syncthreads();
  float acc = finz(ldin(bd, pp * OD + t, bf));
  for (int h = 0; h < HD; ++h) acc += sf[h] * ldin(Wd, (pp * HD + h) * OD + t, bf);
  acc = finz(acc);
  float mx = acc;
#pragma unroll
  for (int off = 32; off > 0; off >>= 1) mx = fmaxf(mx, __shfl_xor(mx, off, 64));
  float ex = __expf(acc - mx);
  float s = ex;
#pragma unroll
  for (int off = 32; off > 0; off >>= 1) s += __shfl_xor(s, off, 64);
  float r = finz(acc - mx - logf(s));
  const int oi = (pp * NN + n) * OD + t;
  if (bf) ((bf16*)out)[oi] = __float2bfloat16(r);
  else    ((float*)out)[oi] = r;
}

extern "C" void kernel_launch(void* const* d_in, const int* in_sizes, int n_in,
                              void* d_out, int out_size, void* d_ws, size_t ws_size,
                              hipStream_t stream) {
  const void* xa   = d_in[0];
  const int*  nbrs = (const int*)d_in[1];
  const void* fmsg = d_in[2];
  const void* We   = d_in[3];
  const void* be   = d_in[4];
  const void* Wq   = d_in[5];
  const void* bq   = d_in[6];
  const void* Wk   = d_in[7];
  const void* bk   = d_in[8];
  const void* Wr   = d_in[9];
  const void* br   = d_in[10];
  const void* Wm   = d_in[11];
  const void* bm   = d_in[12];
  const void* Wd   = d_in[13];
  const void* bd   = d_in[14];
  const int*  dS   = (const int*)d_in[15];
  (void)d_ws; (void)ws_size; (void)in_sizes; (void)n_in; (void)out_size;

  k_bfs<<<dim3(1), dim3(1024), 0, stream>>>((const unsigned*)xa, nbrs, dS);
  k_tr<<<dim3(16), dim3(256), 0, stream>>>(Wk);
  k_rank<<<dim3(NN), dim3(64), 0, stream>>>();
  k_lvl<<<dim3(1), dim3(1024), 0, stream>>>(dS);
  k_weights<<<dim3(HD + 1 + NN), dim3(256), 0, stream>>>(xa, We, be, Wr, bq, bk);
  k_wqk<<<dim3(HD / BATCH), dim3(256), 0, stream>>>(Wq, bk);
  for (int l = 0; l < MAXL - 1; ++l)
    k_level<<<dim3(512), dim3(256), 0, stream>>>(fmsg, br, Wm, bm, dS, l, 0);
  k_level<<<dim3(1), dim3(256), 0, stream>>>(fmsg, br, Wm, bm, dS, MAXL - 1, 1);
  k_out<<<dim3(PD * NN), dim3(OD), 0, stream>>>(Wd, bd, d_out);
}